// Round 12
// baseline (133.543 us; speedup 1.0000x reference)
//
#include <hip/hip_runtime.h>

typedef __bf16 bf16;
typedef __bf16 bf16x8 __attribute__((ext_vector_type(8)));
typedef __bf16 bf16x4 __attribute__((ext_vector_type(4)));
typedef float  f32x4  __attribute__((ext_vector_type(4)));
typedef float  f32x16 __attribute__((ext_vector_type(16)));

constexpr int NCLUS  = 8;
constexpr int HDIM   = 256;
constexpr int DIN    = 36;
constexpr int SEGCAP = 16384;          // per-cluster index capacity (mean 8192)
constexpr int CURPAD = 32;             // cursor entries 128 B apart
constexpr int SCAT_BLKS = 256;         // 256 x 256 threads = 65536 points
constexpr int PREP_ROWS = NCLUS * HDIM + NCLUS * 3 * HDIM + NCLUS * 3;   // 8216
constexpr int PREP_BLKS = (PREP_ROWS + 3) / 4;
constexpr int MAXT   = 160;            // 64-pt tiles/cluster covered (mean 128)
constexpr int MLP_BLKS = NCLUS * MAXT;

// Activation buffer: 64 x 256 bf16 = 32768 B exact (R8-proven best).
// XOR swizzle on element bits 3..5 preserves 8-elem alignment, breaks conflicts.
__device__ __forceinline__ int swz(int p, int col) {
    return p * 256 + (col ^ ((p & 7) << 3));
}

// ---------------- workspace layout (bytes) ----------------
constexpr size_t OFF_ORDER = 4096;
constexpr size_t OFF_PIN   = OFF_ORDER + (size_t)NCLUS * SEGCAP * 4;
constexpr size_t OFF_PMID  = OFF_PIN + (size_t)NCLUS * 64 * 256 * 2;
constexpr size_t OFF_PWOUT = OFF_PMID + (size_t)NCLUS * 3 * 256 * 256 * 2;

// 32x32x16 A-fragment map (weights): for weight row m, element k:
//   frag-lane fl = ((k>>3)&1)*32 + (m&31), j = k&7, tile (kt=k>>4, mt=m>>5)
//   packed idx = ((kt*8 + mt)*64 + fl)*8 + j        (8 mt tiles per 256 outcols)
// Mid layers: 16 kt -> 65536 elems/layer; input layer (K padded to 64): 4 kt -> 16384.
// pwout keeps the 16x16 A-frag map (final layer unchanged).
__global__ __launch_bounds__(256) void setup_kernel(
    const int* __restrict__ cid, int* __restrict__ cursor, int* __restrict__ order,
    const float* __restrict__ V_in,  const float* __restrict__ g_in,
    const float* __restrict__ V_mid, const float* __restrict__ g_mid,
    const float* __restrict__ V_out, const float* __restrict__ g_out,
    bf16* __restrict__ pin, bf16* __restrict__ pmid, bf16* __restrict__ pwout) {
    const int tid = threadIdx.x;
    const int wv = tid >> 6, lane = tid & 63;

    if (blockIdx.x < SCAT_BLKS) {
        __shared__ int bhist[NCLUS];
        __shared__ int wbase[4][NCLUS];
        __shared__ int gbase[NCLUS];
        const int i = blockIdx.x * 256 + tid;
        const int c = cid[i];
        if (tid < NCLUS) bhist[tid] = 0;
        __syncthreads();
        unsigned long long masks[NCLUS];
#pragma unroll
        for (int cc = 0; cc < NCLUS; cc++) masks[cc] = __ballot(c == cc);
        const int rank = __popcll(masks[c] & ((1ull << lane) - 1ull));
        if (lane < NCLUS) wbase[wv][lane] = atomicAdd(&bhist[lane], __popcll(masks[lane]));
        __syncthreads();
        if (tid < NCLUS) gbase[tid] = atomicAdd(&cursor[tid * CURPAD], bhist[tid]);
        __syncthreads();
        const int pos = gbase[c] + wbase[wv][c] + rank;
        if (pos < SEGCAP) order[c * SEGCAP + pos] = i;
        return;
    }

    const int row = (blockIdx.x - SCAT_BLKS) * 4 + wv;
    if (row >= PREP_ROWS) return;

    if (row < NCLUS * HDIM) {                                // input layer: [C,H,36]
        const int c = row >> 8, m = row & 255;
        const float* vrow = V_in + (size_t)row * DIN;
        float v = (lane < DIN) ? vrow[lane] : 0.f;
        float ss = v * v;
#pragma unroll
        for (int off = 32; off; off >>= 1) ss += __shfl_xor(ss, off);
        const float scale = g_in[row] / sqrtf(ss);
        const int k = lane;                                  // 0..63 (zero-padded past 35)
        const int fl = (((k >> 3) & 1) << 5) | (m & 31);
        const int idx = (((k >> 4) * 8 + (m >> 5)) * 64 + fl) * 8 + (k & 7);
        pin[(size_t)c * 16384 + idx] = (bf16)(v * scale);
    } else if (row < NCLUS * HDIM + NCLUS * 3 * HDIM) {      // mid: [C,3,H,H]
        const int r2 = row - NCLUS * HDIM;
        const int cl = r2 >> 8, m = r2 & 255;
        const float4 v4 = *(const float4*)(V_mid + (size_t)r2 * 256 + lane * 4);
        float ss = v4.x * v4.x + v4.y * v4.y + v4.z * v4.z + v4.w * v4.w;
#pragma unroll
        for (int off = 32; off; off >>= 1) ss += __shfl_xor(ss, off);
        const float scale = g_mid[cl * 256 + m] / sqrtf(ss);
        const int k = lane * 4;                              // 4 consecutive k per thread
        const int fl = (((k >> 3) & 1) << 5) | (m & 31);
        const int idx = (((k >> 4) * 8 + (m >> 5)) * 64 + fl) * 8 + (k & 7);
        bf16x4 o = { (bf16)(v4.x * scale), (bf16)(v4.y * scale),
                     (bf16)(v4.z * scale), (bf16)(v4.w * scale) };
        *(bf16x4*)(pmid + (size_t)cl * 65536 + idx) = o;     // idx%8 in {0,4} -> 8 B aligned
    } else {                                                 // out rows: [C,3,H] -> 16x16 A-frag
        const int r3 = row - (NCLUS * HDIM + NCLUS * 3 * HDIM);  // 0..23
        const int c = r3 / 3, o = r3 % 3;
        const float4 v4 = *(const float4*)(V_out + (size_t)r3 * 256 + lane * 4);
        float ss = v4.x * v4.x + v4.y * v4.y + v4.z * v4.z + v4.w * v4.w;
#pragma unroll
        for (int off = 32; off; off >>= 1) ss += __shfl_xor(ss, off);
        const float scale = g_out[r3] / sqrtf(ss);
        const int k = lane * 4;
        const int fl = (((k & 31) >> 3) << 4) | o;
        const int idx = (k >> 5) * 512 + fl * 8 + (k & 7);
        bf16x4 ov = { (bf16)(v4.x * scale), (bf16)(v4.y * scale),
                      (bf16)(v4.z * scale), (bf16)(v4.w * scale) };
        *(bf16x4*)(pwout + (size_t)c * 4096 + idx) = ov;
    }
}

// One layer in place: H[64,256] = relu(W @ H^T)^T using 32x32x16 MFMA (R12: halves
// MFMA instruction count vs 16x16x32 at identical operand bytes -> shorter issue
// path). Wave w owns outcols [64w,+64) x all 64 points as 2x2 tiles of 32x32:
// acc[2][2] f32x16 = 64 AGPR (same as R8). kt-PAIRED k-loop (K=32/iter) with
// depth-2 a-ring (3 slots x 4 frags) = R8-equivalent L2 latency coverage.
// A-frag: m=lane&31, k=(lane>>5)*8+j. B-frag mirror: n=lane&31 (point).
// D: col=lane&31 (point), row=(reg&3)+8*(reg>>2)+4*(lane>>5) (outcol).
template <int KP>   // kt-pairs: mid = 8 (K=256), input = 2 (K=64)
__device__ __forceinline__ void layer_fused(bf16* __restrict__ buf,
                                            const bf16* __restrict__ wp,
                                            const float* __restrict__ bias,
                                            int lane, int w) {
    const int l31 = lane & 31, half = lane >> 5;
    f32x16 acc[2][2];   // [mt][nt]
#pragma unroll
    for (int mt = 0; mt < 2; mt++)
#pragma unroll
        for (int nt = 0; nt < 2; nt++)
#pragma unroll
            for (int i = 0; i < 16; i++) acc[mt][nt][i] = 0.f;

    // a-frag address for (kt, mt): wp + ((kt*8 + (2w+mt))*64 + lane)*8, lane-linear 16B.
    bf16x8 a[3][2][2];  // [slot][kk][mt]
#pragma unroll
    for (int kk = 0; kk < 2; kk++)
#pragma unroll
        for (int mt = 0; mt < 2; mt++)
            a[0][kk][mt] = *(const bf16x8*)(wp + (size_t)((((0 * 2 + kk) * 8 + (2 * w + mt)) * 64 + lane) * 8));
    if (KP > 1)
#pragma unroll
        for (int kk = 0; kk < 2; kk++)
#pragma unroll
            for (int mt = 0; mt < 2; mt++)
                a[1][kk][mt] = *(const bf16x8*)(wp + (size_t)((((1 * 2 + kk) * 8 + (2 * w + mt)) * 64 + lane) * 8));

#pragma unroll
    for (int pr = 0; pr < KP; pr++) {
        if (pr + 2 < KP) {
            const int slot = (pr + 2) % 3;
#pragma unroll
            for (int kk = 0; kk < 2; kk++)
#pragma unroll
                for (int mt = 0; mt < 2; mt++)
                    a[slot][kk][mt] = *(const bf16x8*)(wp + (size_t)(((((pr + 2) * 2 + kk) * 8 + (2 * w + mt)) * 64 + lane) * 8));
        }
        bf16x8 b[2][2];  // [kk][nt]
#pragma unroll
        for (int kk = 0; kk < 2; kk++)
#pragma unroll
            for (int nt = 0; nt < 2; nt++)
                b[kk][nt] = *(const bf16x8*)(buf + swz(nt * 32 + l31, (pr * 2 + kk) * 16 + half * 8));
        const int cur = pr % 3;
#pragma unroll
        for (int kk = 0; kk < 2; kk++)
#pragma unroll
            for (int mt = 0; mt < 2; mt++)
#pragma unroll
                for (int nt = 0; nt < 2; nt++)
                    acc[mt][nt] = __builtin_amdgcn_mfma_f32_32x32x16_bf16(a[cur][kk][mt], b[kk][nt],
                                                                          acc[mt][nt], 0, 0, 0);
    }
    __syncthreads();   // all reads of buf done
#pragma unroll
    for (int mt = 0; mt < 2; mt++)
#pragma unroll
        for (int nt = 0; nt < 2; nt++) {
            const int n = nt * 32 + l31;                 // point
#pragma unroll
            for (int g = 0; g < 4; g++) {
                const int m0 = 64 * w + 32 * mt + 8 * g + 4 * half;   // 4 consecutive outcols
                const float4 bv = *(const float4*)(bias + m0);
                float v0 = acc[mt][nt][4 * g + 0] + bv.x;
                float v1 = acc[mt][nt][4 * g + 1] + bv.y;
                float v2 = acc[mt][nt][4 * g + 2] + bv.z;
                float v3 = acc[mt][nt][4 * g + 3] + bv.w;
                bf16x4 o = { (bf16)(v0 > 0.f ? v0 : 0.f), (bf16)(v1 > 0.f ? v1 : 0.f),
                             (bf16)(v2 > 0.f ? v2 : 0.f), (bf16)(v3 > 0.f ? v3 : 0.f) };
                *(bf16x4*)(buf + swz(n, m0)) = o;        // 8-B aligned
            }
        }
    __syncthreads();   // buf ready for next layer
}

__global__ __launch_bounds__(256, 3) void mlp_kernel(
    const float* __restrict__ X,
    const float* __restrict__ b_in, const float* __restrict__ b_mid,
    const float* __restrict__ b_out,
    const int* __restrict__ counts, const int* __restrict__ order,
    const bf16* __restrict__ pin, const bf16* __restrict__ pmid,
    const bf16* __restrict__ pwout, float* __restrict__ out) {
    // Cluster->XCD pinning (round-5: FETCH 15.5 -> 4.4 MB).
    const int c = blockIdx.x & 7;
    const int tile = blockIdx.x >> 3;
    int count = counts[c * CURPAD];
    if (count > SEGCAP) count = SEGCAP;
    const int s0 = tile * 64;
    if (s0 >= count) return;

    __shared__ __align__(16) bf16 buf[64 * 256];    // 32768 B exact, the ONLY LDS

    const int tid = threadIdx.x;
    const int lane = tid & 63;
    const int w = tid >> 6;
    const int quad = lane >> 4, l15 = lane & 15;

    // Positional encoding, no LDS staging: thread t owns point p = t>>2,
    // cols [(t&3)*16, +16). order/X read straight from global (L2).
    {
        const int p = tid >> 2;
        const int g = s0 + p;
        const int oidx = order[c * SEGCAP + (g < count ? g : s0)];
        const float x0 = X[(size_t)oidx * 3 + 0];
        const float x1 = X[(size_t)oidx * 3 + 1];
        const float x2 = X[(size_t)oidx * 3 + 2];
        const int cb = (tid & 3) * 16;
        bf16 vals[16];
#pragma unroll
        for (int j = 0; j < 16; j++) {
            const int col = cb + j;
            float val = 0.f;
            if (col < DIN) {
                const int f = col / 6, r = col - f * 6;
                const float xi = (r == 0 || r == 3) ? x0 : ((r == 1 || r == 4) ? x1 : x2);
                const float xx = xi * (float)(1 << f);
                val = (r < 3) ? __sinf(xx) : __cosf(xx);
            }
            vals[j] = (bf16)val;
        }
        *(bf16x8*)(buf + swz(p, cb))     = *(const bf16x8*)&vals[0];
        *(bf16x8*)(buf + swz(p, cb + 8)) = *(const bf16x8*)&vals[8];
    }
    __syncthreads();

    layer_fused<2>(buf, pin + (size_t)c * 16384, b_in + c * 256, lane, w);
    layer_fused<8>(buf, pmid + (size_t)(c * 3 + 0) * 65536, b_mid + (c * 3 + 0) * 256, lane, w);
    layer_fused<8>(buf, pmid + (size_t)(c * 3 + 1) * 65536, b_mid + (c * 3 + 1) * 256, lane, w);
    layer_fused<8>(buf, pmid + (size_t)(c * 3 + 2) * 65536, b_mid + (c * 3 + 2) * 256, lane, w);

    // Final 256 -> 3 + tanh via one 16x16x32 MFMA tile per wave (16 points each).
    {
        const bf16* wa = pwout + (size_t)c * 4096;
        f32x4 acc4 = (f32x4){0.f, 0.f, 0.f, 0.f};
#pragma unroll
        for (int ks = 0; ks < 8; ks++) {
            const bf16x8 af = *(const bf16x8*)(wa + ks * 512 + lane * 8);
            const bf16x8 bfr = *(const bf16x8*)(buf + swz(w * 16 + l15, ks * 32 + quad * 8));
            acc4 = __builtin_amdgcn_mfma_f32_16x16x32_bf16(af, bfr, acc4, 0, 0, 0);
        }
        if (quad == 0) {
            const int p = w * 16 + l15;
            if (s0 + p < count) {
                const int oidx = order[c * SEGCAP + s0 + p];
                float* op = out + (size_t)oidx * 3;
                op[0] = tanhf(acc4[0] + b_out[c * 3 + 0]);
                op[1] = tanhf(acc4[1] + b_out[c * 3 + 1]);
                op[2] = tanhf(acc4[2] + b_out[c * 3 + 2]);
            }
        }
    }
}

extern "C" void kernel_launch(void* const* d_in, const int* in_sizes, int n_in,
                              void* d_out, int out_size, void* d_ws, size_t ws_size,
                              hipStream_t stream) {
    const float* X     = (const float*)d_in[0];
    const int*   cid   = (const int*)d_in[1];
    const float* V_in  = (const float*)d_in[2];
    const float* g_in  = (const float*)d_in[3];
    const float* b_in  = (const float*)d_in[4];
    const float* V_mid = (const float*)d_in[5];
    const float* g_mid = (const float*)d_in[6];
    const float* b_mid = (const float*)d_in[7];
    const float* V_out = (const float*)d_in[8];
    const float* g_out = (const float*)d_in[9];
    const float* b_out = (const float*)d_in[10];
    float* out = (float*)d_out;

    char* ws = (char*)d_ws;
    int*   cursor = (int*)ws;
    int*   order  = (int*)(ws + OFF_ORDER);
    bf16*  pin    = (bf16*)(ws + OFF_PIN);
    bf16*  pmid   = (bf16*)(ws + OFF_PMID);
    bf16*  pwout  = (bf16*)(ws + OFF_PWOUT);

    hipMemsetAsync(cursor, 0, NCLUS * CURPAD * sizeof(int), stream);
    setup_kernel<<<SCAT_BLKS + PREP_BLKS, 256, 0, stream>>>(
        cid, cursor, order, V_in, g_in, V_mid, g_mid, V_out, g_out, pin, pmid, pwout);
    mlp_kernel<<<MLP_BLKS, 256, 0, stream>>>(X, b_in, b_mid, b_out, cursor, order,
                                             pin, pmid, pwout, out);
}

// Round 13
// 120.552 us; speedup vs baseline: 1.1078x; 1.1078x over previous
//
#include <hip/hip_runtime.h>

typedef __bf16 bf16;
typedef __bf16 bf16x8 __attribute__((ext_vector_type(8)));
typedef __bf16 bf16x4 __attribute__((ext_vector_type(4)));
typedef float  f32x4  __attribute__((ext_vector_type(4)));

constexpr int NCLUS  = 8;
constexpr int HDIM   = 256;
constexpr int DIN    = 36;
constexpr int SEGCAP = 16384;          // per-cluster index capacity (mean 8192)
constexpr int CURPAD = 32;             // cursor entries 128 B apart
constexpr int SCAT_BLKS = 256;         // 256 x 256 threads = 65536 points
constexpr int PREP_ROWS = NCLUS * HDIM + NCLUS * 3 * HDIM + NCLUS * 3;   // 8216
constexpr int PREP_BLKS = (PREP_ROWS + 3) / 4;
constexpr int MAXT   = 160;            // 64-pt tiles/cluster covered (mean 128)
constexpr int MLP_BLKS = NCLUS * MAXT;

// Activation buffer: 64 x 256 bf16 = 32768 B exact (R8-proven best).
// XOR swizzle on element bits 3..5 preserves 8-elem alignment, breaks conflicts.
__device__ __forceinline__ int swz(int p, int col) {
    return p * 256 + (col ^ ((p & 7) << 3));
}

// ---------------- workspace layout (bytes) ----------------
constexpr size_t OFF_ORDER = 4096;
constexpr size_t OFF_PIN   = OFF_ORDER + (size_t)NCLUS * SEGCAP * 4;
constexpr size_t OFF_PMID  = OFF_PIN + (size_t)NCLUS * 64 * 256 * 2;
constexpr size_t OFF_PWOUT = OFF_PMID + (size_t)NCLUS * 3 * 256 * 256 * 2;

// Fused setup: blocks [0,256) partition points by cluster; the rest weight-norm+pack.
// A-frag map (row m, element k): lane=((k&31)>>3)*16+(m&15), j=k&7,
//   idx = ((k>>5)*16 + (m>>4))*512 + lane*8 + j.   (R8 16x16 map — R12's 32x32 reverted)
__global__ __launch_bounds__(256) void setup_kernel(
    const int* __restrict__ cid, int* __restrict__ cursor, int* __restrict__ order,
    const float* __restrict__ V_in,  const float* __restrict__ g_in,
    const float* __restrict__ V_mid, const float* __restrict__ g_mid,
    const float* __restrict__ V_out, const float* __restrict__ g_out,
    bf16* __restrict__ pin, bf16* __restrict__ pmid, bf16* __restrict__ pwout) {
    const int tid = threadIdx.x;
    const int wv = tid >> 6, lane = tid & 63;

    if (blockIdx.x < SCAT_BLKS) {
        __shared__ int bhist[NCLUS];
        __shared__ int wbase[4][NCLUS];
        __shared__ int gbase[NCLUS];
        const int i = blockIdx.x * 256 + tid;
        const int c = cid[i];
        if (tid < NCLUS) bhist[tid] = 0;
        __syncthreads();
        unsigned long long masks[NCLUS];
#pragma unroll
        for (int cc = 0; cc < NCLUS; cc++) masks[cc] = __ballot(c == cc);
        const int rank = __popcll(masks[c] & ((1ull << lane) - 1ull));
        if (lane < NCLUS) wbase[wv][lane] = atomicAdd(&bhist[lane], __popcll(masks[lane]));
        __syncthreads();
        if (tid < NCLUS) gbase[tid] = atomicAdd(&cursor[tid * CURPAD], bhist[tid]);
        __syncthreads();
        const int pos = gbase[c] + wbase[wv][c] + rank;
        if (pos < SEGCAP) order[c * SEGCAP + pos] = i;
        return;
    }

    const int row = (blockIdx.x - SCAT_BLKS) * 4 + wv;
    if (row >= PREP_ROWS) return;

    if (row < NCLUS * HDIM) {                                // input layer: [C,H,36]
        const int c = row >> 8, m = row & 255;
        const float* vrow = V_in + (size_t)row * DIN;
        float v = (lane < DIN) ? vrow[lane] : 0.f;
        float ss = v * v;
#pragma unroll
        for (int off = 32; off; off >>= 1) ss += __shfl_xor(ss, off);
        const float scale = g_in[row] / sqrtf(ss);
        const int k = lane;
        const int fl = (((k & 31) >> 3) << 4) | (m & 15);
        const int idx = ((k >> 5) * 16 + (m >> 4)) * 512 + fl * 8 + (k & 7);
        pin[(size_t)c * 16384 + idx] = (bf16)(v * scale);
    } else if (row < NCLUS * HDIM + NCLUS * 3 * HDIM) {      // mid: [C,3,H,H]
        const int r2 = row - NCLUS * HDIM;
        const int cl = r2 >> 8, m = r2 & 255;
        const float4 v4 = *(const float4*)(V_mid + (size_t)r2 * 256 + lane * 4);
        float ss = v4.x * v4.x + v4.y * v4.y + v4.z * v4.z + v4.w * v4.w;
#pragma unroll
        for (int off = 32; off; off >>= 1) ss += __shfl_xor(ss, off);
        const float scale = g_mid[cl * 256 + m] / sqrtf(ss);
        const int k = lane * 4;
        const int fl = (((k & 31) >> 3) << 4) | (m & 15);
        const int idx = ((k >> 5) * 16 + (m >> 4)) * 512 + fl * 8 + (k & 7);
        bf16x4 o = { (bf16)(v4.x * scale), (bf16)(v4.y * scale),
                     (bf16)(v4.z * scale), (bf16)(v4.w * scale) };
        *(bf16x4*)(pmid + (size_t)cl * 65536 + idx) = o;
    } else {                                                 // out rows: [C,3,H] -> A-frag tile
        const int r3 = row - (NCLUS * HDIM + NCLUS * 3 * HDIM);  // 0..23
        const int c = r3 / 3, o = r3 % 3;
        const float4 v4 = *(const float4*)(V_out + (size_t)r3 * 256 + lane * 4);
        float ss = v4.x * v4.x + v4.y * v4.y + v4.z * v4.z + v4.w * v4.w;
#pragma unroll
        for (int off = 32; off; off >>= 1) ss += __shfl_xor(ss, off);
        const float scale = g_out[r3] / sqrtf(ss);
        const int k = lane * 4;
        const int fl = (((k & 31) >> 3) << 4) | o;
        const int idx = (k >> 5) * 512 + fl * 8 + (k & 7);
        bf16x4 ov = { (bf16)(v4.x * scale), (bf16)(v4.y * scale),
                      (bf16)(v4.z * scale), (bf16)(v4.w * scale) };
        *(bf16x4*)(pwout + (size_t)c * 4096 + idx) = ov;
    }
}

// One layer in place: H[64,256] = relu(W @ H^T)^T (R8 tiling). Wave w owns outcols
// [64w,64w+64) x all 64 points: acc 4x4 = 64 AGPR. NO software prefetch: a[4] and
// b[4] loaded in-loop (minimum liveness, ~50-60 VGPR total) so the block fits
// 4 waves/SIMD under __launch_bounds__(256,4) WITHOUT spilling (R11 spilled at
// lookahead-1's +16 regs; R10/R11 lesson: spill = 30+ MB HBM round-trips).
// The bet: pure TLP (4 waves/SIMD) covers in-loop L2 (~200cyc) + LDS (~120cyc)
// latency that the a-ring used to cover with ILP.
// D: col(lane&15)=point, row(quad*4+reg)=outcol -> epilogue = 16 x ds_write_b64.
template <int KSTEPS>
__device__ __forceinline__ void layer_fused(bf16* __restrict__ buf,
                                            const bf16* __restrict__ wp,
                                            const float* __restrict__ bias,
                                            int lane, int w) {
    const int quad = lane >> 4, l15 = lane & 15;
    f32x4 acc[4][4];   // [mt][nt]
#pragma unroll
    for (int mt = 0; mt < 4; mt++)
#pragma unroll
        for (int nt = 0; nt < 4; nt++) acc[mt][nt] = (f32x4){0.f, 0.f, 0.f, 0.f};

#pragma unroll
    for (int ks = 0; ks < KSTEPS; ks++) {
        bf16x8 a[4], b[4];
#pragma unroll
        for (int mt = 0; mt < 4; mt++)
            a[mt] = *(const bf16x8*)(wp + (size_t)((ks * 16 + (4 * w + mt)) * 512 + lane * 8));
#pragma unroll
        for (int nt = 0; nt < 4; nt++)
            b[nt] = *(const bf16x8*)(buf + swz(nt * 16 + l15, ks * 32 + quad * 8));
#pragma unroll
        for (int mt = 0; mt < 4; mt++)
#pragma unroll
            for (int nt = 0; nt < 4; nt++)
                acc[mt][nt] = __builtin_amdgcn_mfma_f32_16x16x32_bf16(a[mt], b[nt],
                                                                      acc[mt][nt], 0, 0, 0);
    }
    __syncthreads();   // all reads of buf done
#pragma unroll
    for (int mt = 0; mt < 4; mt++) {
        const int m0 = 64 * w + mt * 16 + quad * 4;
        const float4 bv = *(const float4*)(bias + m0);
#pragma unroll
        for (int nt = 0; nt < 4; nt++) {
            const int p = nt * 16 + l15;
            float v0 = acc[mt][nt][0] + bv.x, v1 = acc[mt][nt][1] + bv.y;
            float v2 = acc[mt][nt][2] + bv.z, v3 = acc[mt][nt][3] + bv.w;
            bf16x4 o = { (bf16)(v0 > 0.f ? v0 : 0.f), (bf16)(v1 > 0.f ? v1 : 0.f),
                         (bf16)(v2 > 0.f ? v2 : 0.f), (bf16)(v3 > 0.f ? v3 : 0.f) };
            *(bf16x4*)(buf + swz(p, m0)) = o;   // 8-B aligned (m0 % 4 == 0, swz keeps bits 0..2)
        }
    }
    __syncthreads();   // buf ready for next layer
}

__global__ __launch_bounds__(256, 4) void mlp_kernel(
    const float* __restrict__ X,
    const float* __restrict__ b_in, const float* __restrict__ b_mid,
    const float* __restrict__ b_out,
    const int* __restrict__ counts, const int* __restrict__ order,
    const bf16* __restrict__ pin, const bf16* __restrict__ pmid,
    const bf16* __restrict__ pwout, float* __restrict__ out) {
    // Cluster->XCD pinning (round-5: FETCH 15.5 -> 4.4 MB).
    const int c = blockIdx.x & 7;
    const int tile = blockIdx.x >> 3;
    int count = counts[c * CURPAD];
    if (count > SEGCAP) count = SEGCAP;
    const int s0 = tile * 64;
    if (s0 >= count) return;

    __shared__ __align__(16) bf16 buf[64 * 256];    // 32768 B exact, the ONLY LDS

    const int tid = threadIdx.x;
    const int lane = tid & 63;
    const int w = tid >> 6;
    const int quad = lane >> 4, l15 = lane & 15;

    // Positional encoding, no LDS staging: thread t owns point p = t>>2,
    // cols [(t&3)*16, +16). order/X read straight from global (L2).
    {
        const int p = tid >> 2;
        const int g = s0 + p;
        const int oidx = order[c * SEGCAP + (g < count ? g : s0)];
        const float x0 = X[(size_t)oidx * 3 + 0];
        const float x1 = X[(size_t)oidx * 3 + 1];
        const float x2 = X[(size_t)oidx * 3 + 2];
        const int cb = (tid & 3) * 16;
        bf16 vals[16];
#pragma unroll
        for (int j = 0; j < 16; j++) {
            const int col = cb + j;
            float val = 0.f;
            if (col < DIN) {
                const int f = col / 6, r = col - f * 6;
                const float xi = (r == 0 || r == 3) ? x0 : ((r == 1 || r == 4) ? x1 : x2);
                const float xx = xi * (float)(1 << f);
                val = (r < 3) ? __sinf(xx) : __cosf(xx);
            }
            vals[j] = (bf16)val;
        }
        *(bf16x8*)(buf + swz(p, cb))     = *(const bf16x8*)&vals[0];
        *(bf16x8*)(buf + swz(p, cb + 8)) = *(const bf16x8*)&vals[8];
    }
    __syncthreads();

    layer_fused<2>(buf, pin + (size_t)c * 16384, b_in + c * 256, lane, w);
    layer_fused<8>(buf, pmid + (size_t)(c * 3 + 0) * 65536, b_mid + (c * 3 + 0) * 256, lane, w);
    layer_fused<8>(buf, pmid + (size_t)(c * 3 + 1) * 65536, b_mid + (c * 3 + 1) * 256, lane, w);
    layer_fused<8>(buf, pmid + (size_t)(c * 3 + 2) * 65536, b_mid + (c * 3 + 2) * 256, lane, w);

    // Final 256 -> 3 + tanh via one 16x16 MFMA tile per wave (16 points each).
    {
        const bf16* wa = pwout + (size_t)c * 4096;
        f32x4 acc4 = (f32x4){0.f, 0.f, 0.f, 0.f};
#pragma unroll
        for (int ks = 0; ks < 8; ks++) {
            const bf16x8 af = *(const bf16x8*)(wa + ks * 512 + lane * 8);
            const bf16x8 bfr = *(const bf16x8*)(buf + swz(w * 16 + l15, ks * 32 + quad * 8));
            acc4 = __builtin_amdgcn_mfma_f32_16x16x32_bf16(af, bfr, acc4, 0, 0, 0);
        }
        if (quad == 0) {
            const int p = w * 16 + l15;
            if (s0 + p < count) {
                const int oidx = order[c * SEGCAP + s0 + p];
                float* op = out + (size_t)oidx * 3;
                op[0] = tanhf(acc4[0] + b_out[c * 3 + 0]);
                op[1] = tanhf(acc4[1] + b_out[c * 3 + 1]);
                op[2] = tanhf(acc4[2] + b_out[c * 3 + 2]);
            }
        }
    }
}

extern "C" void kernel_launch(void* const* d_in, const int* in_sizes, int n_in,
                              void* d_out, int out_size, void* d_ws, size_t ws_size,
                              hipStream_t stream) {
    const float* X     = (const float*)d_in[0];
    const int*   cid   = (const int*)d_in[1];
    const float* V_in  = (const float*)d_in[2];
    const float* g_in  = (const float*)d_in[3];
    const float* b_in  = (const float*)d_in[4];
    const float* V_mid = (const float*)d_in[5];
    const float* g_mid = (const float*)d_in[6];
    const float* b_mid = (const float*)d_in[7];
    const float* V_out = (const float*)d_in[8];
    const float* g_out = (const float*)d_in[9];
    const float* b_out = (const float*)d_in[10];
    float* out = (float*)d_out;

    char* ws = (char*)d_ws;
    int*   cursor = (int*)ws;
    int*   order  = (int*)(ws + OFF_ORDER);
    bf16*  pin    = (bf16*)(ws + OFF_PIN);
    bf16*  pmid   = (bf16*)(ws + OFF_PMID);
    bf16*  pwout  = (bf16*)(ws + OFF_PWOUT);

    hipMemsetAsync(cursor, 0, NCLUS * CURPAD * sizeof(int), stream);
    setup_kernel<<<SCAT_BLKS + PREP_BLKS, 256, 0, stream>>>(
        cid, cursor, order, V_in, g_in, V_mid, g_mid, V_out, g_out, pin, pmid, pwout);
    mlp_kernel<<<MLP_BLKS, 256, 0, stream>>>(X, b_in, b_mid, b_out, cursor, order,
                                             pin, pmid, pwout, out);
}